// Round 10
// baseline (405.712 us; speedup 1.0000x reference)
//
#include <hip/hip_runtime.h>
#include <hip/hip_fp8.h>
#include <math.h>

#define N_NODES 100000
#define N_EDGES 1600000
#define F_IN 256
#define F_H 128
#define F_OUT 40

// ---- CSR build via LDS-binned counting sort ----
#define BIN_SHIFT 9
#define BIN_NODES 512                       // 1 << BIN_SHIFT
#define NBIN 196                            // ceil(100000 / 512)
#define CAP 12288                           // per-bin capacity (mean 8163, sigma ~90)
#define CNT_PAD 16                          // one counter per 64B line
#define PART_CHUNK 8192                     // edges per k_part block
#define DEGB 64                             // degree buckets for perm sort

typedef __attribute__((ext_vector_type(8))) short bf16x8;
typedef __attribute__((ext_vector_type(4))) float floatx4;
typedef __attribute__((ext_vector_type(2))) float floatx2;
typedef __attribute__((ext_vector_type(2))) unsigned int uintx2;
typedef __attribute__((ext_vector_type(4))) unsigned int uintx4;

__device__ __forceinline__ unsigned short f2bf(float f) {
    unsigned int u = __float_as_uint(f);
    u += 0x7fffu + ((u >> 16) & 1u);          // RNE (finite inputs)
    return (unsigned short)(u >> 16);
}

// ---- fp8 e4m3 (OCP) encode/decode, native cvt when available ----
#if defined(__has_builtin)
#if __has_builtin(__builtin_amdgcn_cvt_pk_fp8_f32)
#define HAVE_PK_ENC 1
#endif
#if __has_builtin(__builtin_amdgcn_cvt_pk_f32_fp8)
#define HAVE_PK_DEC 1
#endif
#if __has_builtin(__builtin_amdgcn_cvt_f32_fp8)
#define HAVE_SC_DEC 1
#endif
#endif

__device__ __forceinline__ unsigned char f2f8(float f) {
#ifdef HAVE_PK_ENC
    int r = __builtin_amdgcn_cvt_pk_fp8_f32(f, f, 0, false);
    return (unsigned char)(r & 0xff);
#else
    __hip_fp8_e4m3 t(f);
    return (unsigned char)t.__x;
#endif
}
__device__ __forceinline__ float f82f(unsigned char b) {
#ifdef HAVE_SC_DEC
    return __builtin_amdgcn_cvt_f32_fp8((int)b, 0);
#else
    __hip_fp8_e4m3 t; t.__x = (__hip_fp8_storage_t)b;
    return (float)t;
#endif
}
__device__ __forceinline__ floatx2 f8x2tof(unsigned short u) {
#ifdef HAVE_PK_DEC
    return __builtin_amdgcn_cvt_pk_f32_fp8((int)u, false);
#else
    floatx2 r;
    r.x = f82f((unsigned char)(u & 0xff));
    r.y = f82f((unsigned char)(u >> 8));
    return r;
#endif
}

// accumulate 16 fp8 (one uint4) into a[0..15]
__device__ __forceinline__ void acc16(uintx4 u, float* a) {
#pragma unroll
    for (int d = 0; d < 4; ++d) {
        floatx2 lo = f8x2tof((unsigned short)(u[d] & 0xffffu));
        floatx2 hi = f8x2tof((unsigned short)(u[d] >> 16));
        a[d * 4 + 0] += lo.x; a[d * 4 + 1] += lo.y;
        a[d * 4 + 2] += hi.x; a[d * 4 + 3] += hi.y;
    }
}

// ---- phase A: partition edges into NBIN dst-bins (packed src<<9|dloc) ----
__global__ __launch_bounds__(256) void k_part(const int* __restrict__ eidx,
                                              int* __restrict__ gcnt,
                                              unsigned int* __restrict__ parts) {
    __shared__ int hist[4][NBIN];
    __shared__ int sbase[NBIN];
    __shared__ int rcnt[NBIN];
    const int tid = threadIdx.x;
    const int wv = tid >> 6;
    for (int i = tid; i < NBIN; i += 256) {
        hist[0][i] = 0; hist[1][i] = 0; hist[2][i] = 0; hist[3][i] = 0; rcnt[i] = 0;
    }
    __syncthreads();
    const int e0 = blockIdx.x * PART_CHUNK;
    const int e1 = min(e0 + PART_CHUNK, N_EDGES);
    for (int e = e0 + tid; e < e1; e += 256) {
        int d = eidx[N_EDGES + e];
        atomicAdd(&hist[wv][d >> BIN_SHIFT], 1);
    }
    __syncthreads();
    for (int b = tid; b < NBIN; b += 256) {
        int tot = hist[0][b] + hist[1][b] + hist[2][b] + hist[3][b];
        int old = atomicAdd(&gcnt[b * CNT_PAD], tot);
        sbase[b] = b * CAP + old;
    }
    __syncthreads();
    for (int e = e0 + tid; e < e1; e += 256) {
        int d = eidx[N_EDGES + e];          // L2-hot re-read
        int s = eidx[e];
        int b = d >> BIN_SHIFT;
        int r = atomicAdd(&rcnt[b], 1);
        parts[sbase[b] + r] = ((unsigned int)s << BIN_SHIFT) | (unsigned int)(d & (BIN_NODES - 1));
    }
}

// ---- phase B: per-bin CSR build; block g owns nodes [g*512, g*512+512) ----
__global__ __launch_bounds__(256) void k_build(const unsigned int* __restrict__ parts,
                                               const int* __restrict__ gcnt,
                                               int* __restrict__ rowptr,
                                               float* __restrict__ dinv,
                                               int* __restrict__ csr_src) {
    __shared__ int deg[4][BIN_NODES];   // per-wave replicated histogram (8 KB)
    __shared__ int cur[BIN_NODES];
    __shared__ int scan[256];
    const int tid = threadIdx.x;
    const int wv = tid >> 6;
    const int g = blockIdx.x;

    // exclusive scan of bin sizes -> this bin's global edge base
    scan[tid] = (tid < NBIN) ? gcnt[tid * CNT_PAD] : 0;
    __syncthreads();
    for (int off = 1; off < 256; off <<= 1) {
        int v = 0;
        if (tid >= off) v = scan[tid - off];
        __syncthreads();
        if (tid >= off) scan[tid] += v;
        __syncthreads();
    }
    const int binBase = (g == 0) ? 0 : scan[g - 1];
    const int cntg = scan[g] - binBase;

    for (int i = tid; i < BIN_NODES; i += 256) {
        deg[0][i] = 0; deg[1][i] = 0; deg[2][i] = 0; deg[3][i] = 0;
    }
    __syncthreads();

    const unsigned int* pp = parts + (size_t)g * CAP;
    for (int i = tid; i < cntg; i += 256)
        atomicAdd(&deg[wv][pp[i] & (BIN_NODES - 1)], 1);
    __syncthreads();

    // block scan over 512 degrees (thread t owns nodes 2t, 2t+1)
    const int n0 = 2 * tid, n1 = 2 * tid + 1;
    const int d0 = deg[0][n0] + deg[1][n0] + deg[2][n0] + deg[3][n0];
    const int d1 = deg[0][n1] + deg[1][n1] + deg[2][n1] + deg[3][n1];
    scan[tid] = d0 + d1;
    __syncthreads();
    for (int off = 1; off < 256; off <<= 1) {
        int v = 0;
        if (tid >= off) v = scan[tid - off];
        __syncthreads();
        if (tid >= off) scan[tid] += v;
        __syncthreads();
    }
    const int pre = (tid == 0) ? 0 : scan[tid - 1];
    const int p0 = binBase + pre;
    const int p1 = p0 + d0;
    const int node0 = g * BIN_NODES + n0;
    if (node0 < N_NODES)     { rowptr[node0]     = p0; dinv[node0]     = rsqrtf((float)d0 + 1.0f); }
    if (node0 + 1 < N_NODES) { rowptr[node0 + 1] = p1; dinv[node0 + 1] = rsqrtf((float)d1 + 1.0f); }
    cur[n0] = p0;
    cur[n1] = p1;
    __syncthreads();

    for (int i = tid; i < cntg; i += 256) {
        unsigned int u = pp[i];
        int pos = atomicAdd(&cur[u & (BIN_NODES - 1)], 1);
        csr_src[pos] = (int)(u >> BIN_SHIFT);
    }
    if (g == NBIN - 1 && tid == 0) rowptr[N_NODES] = N_EDGES;
}

// ---- degree-bucket histogram (for degree-sorted node permutation) ----
__global__ __launch_bounds__(256) void k_dhist(const int* __restrict__ rowptr,
                                               int* __restrict__ dcnt) {
    __shared__ int h[4][DEGB];
    const int tid = threadIdx.x;
    const int wv = tid >> 6;
    if (tid < DEGB) { h[0][tid] = 0; h[1][tid] = 0; h[2][tid] = 0; h[3][tid] = 0; }
    __syncthreads();
    const int base = blockIdx.x * 1024;
#pragma unroll
    for (int j = 0; j < 4; ++j) {
        int i = base + j * 256 + tid;
        if (i < N_NODES) {
            int d = min(rowptr[i + 1] - rowptr[i], DEGB - 1);
            atomicAdd(&h[wv][d], 1);
        }
    }
    __syncthreads();
    if (tid < DEGB) {
        int tot = h[0][tid] + h[1][tid] + h[2][tid] + h[3][tid];
        if (tot) atomicAdd(&dcnt[tid * CNT_PAD], tot);
    }
}

// ---- exclusive scan of 64 degree buckets (counts -> bases, in place) ----
__global__ void k_dscan(int* dcnt) {
    if (threadIdx.x == 0) {
        int run = 0;
        for (int i = 0; i < DEGB; ++i) {
            int c = dcnt[i * CNT_PAD];
            dcnt[i * CNT_PAD] = run;
            run += c;
        }
    }
}

// ---- scatter nodes into degree-sorted perm ----
__global__ __launch_bounds__(256) void k_dscat(const int* __restrict__ rowptr,
                                               int* __restrict__ dcnt,
                                               int* __restrict__ perm) {
    __shared__ int h[4][DEGB];
    __shared__ int base[DEGB];
    __shared__ int lr[DEGB];
    const int tid = threadIdx.x;
    const int wv = tid >> 6;
    if (tid < DEGB) {
        h[0][tid] = 0; h[1][tid] = 0; h[2][tid] = 0; h[3][tid] = 0; lr[tid] = 0;
    }
    __syncthreads();
    const int nb = blockIdx.x * 1024;
    int dg[4];
#pragma unroll
    for (int j = 0; j < 4; ++j) {
        int i = nb + j * 256 + tid;
        dg[j] = -1;
        if (i < N_NODES) {
            dg[j] = min(rowptr[i + 1] - rowptr[i], DEGB - 1);
            atomicAdd(&h[wv][dg[j]], 1);
        }
    }
    __syncthreads();
    if (tid < DEGB) {
        int tot = h[0][tid] + h[1][tid] + h[2][tid] + h[3][tid];
        base[tid] = tot ? atomicAdd(&dcnt[tid * CNT_PAD], tot) : 0;
    }
    __syncthreads();
#pragma unroll
    for (int j = 0; j < 4; ++j) {
        int i = nb + j * 256 + tid;
        if (dg[j] >= 0) {
            int r = atomicAdd(&lr[dg[j]], 1);
            perm[base[dg[j]] + r] = i;
        }
    }
}

// ---- weight converts + gcnt/dcnt zero (runs FIRST) ----
__global__ void k_cvt_w(const float* __restrict__ W1, const float* __restrict__ W2,
                        short* __restrict__ W1t, short* __restrict__ W2t,
                        int* __restrict__ gcnt, int* __restrict__ dcnt) {
    int b = blockIdx.x, t = threadIdx.x;
    if (b < 128) {
        int idx = b * 256 + t;                 // 32768
        int n = idx >> 8, k = idx & 255;
        W1t[n * 256 + k] = (short)f2bf(W1[k * 128 + n]);
    } else {
        int idx = (b - 128) * 256 + t;         // 6144
        if (idx < 48 * 128) {
            int n = idx >> 7, k = idx & 127;
            float v = (n < F_OUT) ? W2[k * F_OUT + n] : 0.f;
            W2t[n * 128 + k] = (short)f2bf(v);
        }
        if (idx < NBIN * CNT_PAD) gcnt[idx] = 0;
        if (idx < DEGB * CNT_PAD) dcnt[idx] = 0;
    }
}

// ---- GEMM1 (MFMA bf16): h1q[4][N][32](fp8, PLANE-MAJOR) = dinv[row]*(x@W1) ----
// 128-row tile. Full-K B staged into LDS once; A staged per 32-k step.
// Output plane = col/32 so spmm1 plane passes gather from a 3.2MB L2-resident table.
__global__ __launch_bounds__(256) void k_gemm1_mfma(const float* __restrict__ x,
                                                    const short* __restrict__ W1t,
                                                    const float* __restrict__ dinv,
                                                    unsigned char* __restrict__ h1q) {
    __shared__ short As[128 * 40];       // 10 KB, row stride 40 (80 B: 2-way banks, free)
    __shared__ short Bs[128 * 264];      // 67.6 KB, row stride 264
    __shared__ float Ds[128];
    const int tid = threadIdx.x;
    const int row0 = blockIdx.x * 128;
    const int w = tid >> 6, l = tid & 63;
    const int l15 = l & 15, q = l >> 4;
    const int ar = tid >> 1;             // 0..127
    const int ak = (tid & 1) * 16;       // 0 or 16

    // stage full B once: thread t covers row n=t>>1, k-half (t&1)*128
    {
        const int n = tid >> 1;
        const int kh = (tid & 1) * 128;
#pragma unroll
        for (int i = 0; i < 16; ++i)
            *(bf16x8*)&Bs[n * 264 + kh + i * 8] = *(const bf16x8*)&W1t[n * 256 + kh + i * 8];
    }
    if (tid < 128) {
        int r = row0 + tid;
        Ds[tid] = (r < N_NODES) ? dinv[r] : 0.f;
    }

    floatx4 acc[2][8];
#pragma unroll
    for (int a = 0; a < 2; ++a)
#pragma unroll
        for (int nt = 0; nt < 8; ++nt) acc[a][nt] = (floatx4)0.f;

    const bool arow_ok = (row0 + ar) < N_NODES;
    const float* xp = x + (size_t)(row0 + ar) * F_IN;

    for (int k0 = 0; k0 < F_IN; k0 += 32) {
        bf16x8 av0 = (bf16x8)0, av1 = (bf16x8)0;
        if (arow_ok) {
            floatx4 f0 = *(const floatx4*)(xp + k0 + ak);
            floatx4 f1 = *(const floatx4*)(xp + k0 + ak + 4);
            floatx4 f2 = *(const floatx4*)(xp + k0 + ak + 8);
            floatx4 f3 = *(const floatx4*)(xp + k0 + ak + 12);
            av0[0] = (short)f2bf(f0[0]); av0[1] = (short)f2bf(f0[1]);
            av0[2] = (short)f2bf(f0[2]); av0[3] = (short)f2bf(f0[3]);
            av0[4] = (short)f2bf(f1[0]); av0[5] = (short)f2bf(f1[1]);
            av0[6] = (short)f2bf(f1[2]); av0[7] = (short)f2bf(f1[3]);
            av1[0] = (short)f2bf(f2[0]); av1[1] = (short)f2bf(f2[1]);
            av1[2] = (short)f2bf(f2[2]); av1[3] = (short)f2bf(f2[3]);
            av1[4] = (short)f2bf(f3[0]); av1[5] = (short)f2bf(f3[1]);
            av1[6] = (short)f2bf(f3[2]); av1[7] = (short)f2bf(f3[3]);
        }
        __syncthreads();              // also covers the one-time B stage on k0==0
        *(bf16x8*)&As[ar * 40 + ak]     = av0;
        *(bf16x8*)&As[ar * 40 + ak + 8] = av1;
        __syncthreads();

        bf16x8 af[2], bfr[8];
#pragma unroll
        for (int a = 0; a < 2; ++a)
            af[a] = *(const bf16x8*)&As[((w * 2 + a) * 16 + l15) * 40 + q * 8];
#pragma unroll
        for (int nt = 0; nt < 8; ++nt)
            bfr[nt] = *(const bf16x8*)&Bs[(nt * 16 + l15) * 264 + k0 + q * 8];
#pragma unroll
        for (int a = 0; a < 2; ++a)
#pragma unroll
            for (int nt = 0; nt < 8; ++nt)
                acc[a][nt] = __builtin_amdgcn_mfma_f32_16x16x32_bf16(af[a], bfr[nt], acc[a][nt], 0, 0, 0);
    }
#pragma unroll
    for (int a = 0; a < 2; ++a) {
#pragma unroll
        for (int r = 0; r < 4; ++r) {
            const int rl = (w * 2 + a) * 16 + q * 4 + r;
            const int row = row0 + rl;
            if (row < N_NODES) {
                const float ds = Ds[rl];
#pragma unroll
                for (int nt = 0; nt < 8; ++nt)
                    h1q[((size_t)(nt >> 1) * N_NODES + row) * 32 + (nt & 1) * 16 + l15]
                        = f2f8(acc[a][nt][r] * ds);
            }
        }
    }
}

// ---- SpMM1 plane pass: 2 lanes/node x 16B; gather table = 3.2MB (L2-resident) ----
// Degree-sorted perm: 32 nodes/wave have near-equal degree (no divergence waste).
// Same total gather instructions as the single-pass version (E/8 wave-instrs).
__global__ __launch_bounds__(256) void k_spmm1_q(const int* __restrict__ rowptr,
                                                 const int* __restrict__ csr_src,
                                                 const int* __restrict__ perm,
                                                 const uintx4* __restrict__ hq,    // plane rows as 2 uint4
                                                 const float* __restrict__ dinv,
                                                 const float* __restrict__ b1p,    // 32 floats (plane slice)
                                                 unsigned short* __restrict__ aggp) { // agg1b + pl*32
    const int slot = threadIdx.x >> 1;        // 0..127 node slot in block
    const int pq = threadIdx.x & 1;           // 16B half of the 32B plane row
    const int gid = blockIdx.x * 128 + slot;
    if (gid >= N_NODES) return;
    const int node = perm[gid];

    const int beg = rowptr[node];
    const int end = rowptr[node + 1];
    const float dv = dinv[node];

    float accA[16], accB[16];
#pragma unroll
    for (int jj = 0; jj < 16; ++jj) { accA[jj] = 0.f; accB[jj] = 0.f; }
    acc16(hq[(size_t)node * 2 + pq], accA);            // self loop

    int i = beg;
    for (; i + 3 < end; i += 4) {
        int s0 = csr_src[i], s1 = csr_src[i + 1], s2 = csr_src[i + 2], s3 = csr_src[i + 3];
        uintx4 u0 = hq[(size_t)s0 * 2 + pq];
        uintx4 u1 = hq[(size_t)s1 * 2 + pq];
        uintx4 u2 = hq[(size_t)s2 * 2 + pq];
        uintx4 u3 = hq[(size_t)s3 * 2 + pq];
        acc16(u0, accA); acc16(u1, accB);
        acc16(u2, accA); acc16(u3, accB);
    }
    for (; i < end; ++i)
        acc16(hq[(size_t)csr_src[i] * 2 + pq], accA);

    const float* bp = b1p + 16 * pq;
    unsigned int ow[8];
#pragma unroll
    for (int jj = 0; jj < 8; ++jj) {
        float v0 = fmaf(accA[2 * jj]     + accB[2 * jj],     dv, bp[2 * jj]);
        float v1 = fmaf(accA[2 * jj + 1] + accB[2 * jj + 1], dv, bp[2 * jj + 1]);
        v0 = v0 > 0.f ? v0 : 0.f;
        v1 = v1 > 0.f ? v1 : 0.f;
        ow[jj] = ((unsigned int)f2bf(v1) << 16) | f2bf(v0);
    }
    uintx4* op = (uintx4*)(aggp + (size_t)node * F_H + pq * 16);
    uintx4 o0, o1;
    o0[0] = ow[0]; o0[1] = ow[1]; o0[2] = ow[2]; o0[3] = ow[3];
    o1[0] = ow[4]; o1[1] = ow[5]; o1[2] = ow[6]; o1[3] = ow[7];
    op[0] = o0;
    op[1] = o1;
}

// ---- GEMM2 (MFMA bf16): h2f8[N,40](fp8) = dinv[row] * (agg1b[N,128] @ W2) ----
__global__ __launch_bounds__(256) void k_gemm2_mfma(const unsigned short* __restrict__ agg1b,
                                                    const short* __restrict__ W2t,
                                                    const float* __restrict__ dinv,
                                                    unsigned char* __restrict__ h2f8) {
    __shared__ short As[128 * 40];     // 10 KB
    __shared__ short Bs[48 * 136];     // 12.75 KB
    __shared__ float Ds[128];
    const int tid = threadIdx.x;
    // bijective XCD-contiguous swizzle over 782 blocks (782 = 8*97+6)
    const int bidr = blockIdx.x;
    const int kx = bidr & 7, jx = bidr >> 3;
    const int cb = (kx < 6) ? (kx * 98 + jx) : (6 * 98 + (kx - 6) * 97 + jx);
    const int row0 = cb * 128;
    const int w = tid >> 6, l = tid & 63;
    const int l15 = l & 15, q = l >> 4;
    const int ar = tid >> 1;             // 0..127
    const int ak = (tid & 1) * 16;

#pragma unroll
    for (int i = 0; i < 3; ++i) {
        int c = tid * 3 + i;             // 0..767 chunks of 8 bf16
        int n = c >> 4, koff = (c & 15) * 8;
        *(bf16x8*)&Bs[n * 136 + koff] = *(const bf16x8*)&W2t[n * 128 + koff];
    }
    if (tid < 128) {
        int r = row0 + tid;
        Ds[tid] = (r < N_NODES) ? dinv[r] : 0.f;
    }

    floatx4 acc[2][3];
#pragma unroll
    for (int a = 0; a < 2; ++a)
#pragma unroll
        for (int nt = 0; nt < 3; ++nt) acc[a][nt] = (floatx4)0.f;

    const bool arow_ok = (row0 + ar) < N_NODES;
    const unsigned short* ap = agg1b + (size_t)(row0 + ar) * F_H;

    for (int k0 = 0; k0 < F_H; k0 += 32) {
        bf16x8 a0, a1;
        if (arow_ok) {
            a0 = *(const bf16x8*)(ap + k0 + ak);
            a1 = *(const bf16x8*)(ap + k0 + ak + 8);
        } else {
            a0 = (bf16x8)0; a1 = (bf16x8)0;
        }
        *(bf16x8*)&As[ar * 40 + ak]     = a0;
        *(bf16x8*)&As[ar * 40 + ak + 8] = a1;
        __syncthreads();

        bf16x8 af[2], bfr[3];
#pragma unroll
        for (int a = 0; a < 2; ++a)
            af[a] = *(const bf16x8*)&As[((w * 2 + a) * 16 + l15) * 40 + q * 8];
#pragma unroll
        for (int nt = 0; nt < 3; ++nt)
            bfr[nt] = *(const bf16x8*)&Bs[(nt * 16 + l15) * 136 + k0 + q * 8];
#pragma unroll
        for (int a = 0; a < 2; ++a)
#pragma unroll
            for (int nt = 0; nt < 3; ++nt)
                acc[a][nt] = __builtin_amdgcn_mfma_f32_16x16x32_bf16(af[a], bfr[nt], acc[a][nt], 0, 0, 0);
        __syncthreads();
    }
#pragma unroll
    for (int a = 0; a < 2; ++a) {
#pragma unroll
        for (int nt = 0; nt < 3; ++nt) {
            int col = nt * 16 + l15;
#pragma unroll
            for (int r = 0; r < 4; ++r) {
                int rl = (w * 2 + a) * 16 + q * 4 + r;
                int row = row0 + rl;
                if (row < N_NODES && col < F_OUT)
                    h2f8[(size_t)row * F_OUT + col] = f2f8(acc[a][nt][r] * Ds[rl]);
            }
        }
    }
}

// ---- SpMM2 + log_softmax: QUARTER-WAVE (16 lanes) per node, natural order ----
__global__ __launch_bounds__(256) void k_spmm2_lsm(const int* __restrict__ rowptr,
                                                   const int* __restrict__ csr_src,
                                                   const unsigned int* __restrict__ h2d,  // fp8 rows as 10 dwords
                                                   const float* __restrict__ dinv,
                                                   const float* __restrict__ b2,
                                                   float* __restrict__ out) {
    const int qid = threadIdx.x >> 4;         // 0..15 node slot in block
    const int p = threadIdx.x & 15;           // dword index (active p<10)
    int node = blockIdx.x * 16 + qid;
    bool nvalid = node < N_NODES;
    bool valid = nvalid && (p < 10);
    int nd = nvalid ? node : 0;
    int beg = 0, end = 0;
    if (valid) { beg = rowptr[nd]; end = rowptr[nd + 1]; }
    float dv = dinv[nd];

    float A0 = 0.f, A1 = 0.f, A2 = 0.f, A3 = 0.f;
    float B0 = 0.f, B1 = 0.f, B2 = 0.f, B3 = 0.f;
    if (valid) {
        unsigned int su = h2d[(size_t)nd * 10 + p];
        floatx2 t0 = f8x2tof((unsigned short)(su & 0xffffu));
        floatx2 t1 = f8x2tof((unsigned short)(su >> 16));
        A0 = t0.x; A1 = t0.y; A2 = t1.x; A3 = t1.y;   // self loop
    }
    int i = beg;
    for (; i + 1 < end; i += 2) {
        int s0 = csr_src[i], s1 = csr_src[i + 1];
        unsigned int u0 = h2d[(size_t)s0 * 10 + p];
        unsigned int u1 = h2d[(size_t)s1 * 10 + p];
        floatx2 a01 = f8x2tof((unsigned short)(u0 & 0xffffu));
        floatx2 a23 = f8x2tof((unsigned short)(u0 >> 16));
        floatx2 b01 = f8x2tof((unsigned short)(u1 & 0xffffu));
        floatx2 b23 = f8x2tof((unsigned short)(u1 >> 16));
        A0 += a01.x; A1 += a01.y; A2 += a23.x; A3 += a23.y;
        B0 += b01.x; B1 += b01.y; B2 += b23.x; B3 += b23.y;
    }
    if (i < end) {
        unsigned int u0 = h2d[(size_t)csr_src[i] * 10 + p];
        floatx2 a01 = f8x2tof((unsigned short)(u0 & 0xffffu));
        floatx2 a23 = f8x2tof((unsigned short)(u0 >> 16));
        A0 += a01.x; A1 += a01.y; A2 += a23.x; A3 += a23.y;
    }

    float v0 = -INFINITY, v1 = -INFINITY, v2 = -INFINITY, v3 = -INFINITY;
    if (valid) {
        float4 bb = *(const float4*)&b2[4 * p];
        v0 = fmaf(A0 + B0, dv, bb.x);
        v1 = fmaf(A1 + B1, dv, bb.y);
        v2 = fmaf(A2 + B2, dv, bb.z);
        v3 = fmaf(A3 + B3, dv, bb.w);
    }
    float m = fmaxf(fmaxf(v0, v1), fmaxf(v2, v3));
#pragma unroll
    for (int off = 1; off < 16; off <<= 1) m = fmaxf(m, __shfl_xor(m, off, 16));
    float e = 0.f;
    if (valid) e = expf(v0 - m) + expf(v1 - m) + expf(v2 - m) + expf(v3 - m);
#pragma unroll
    for (int off = 1; off < 16; off <<= 1) e += __shfl_xor(e, off, 16);
    if (valid) {
        float ls = logf(e);
        floatx4 o;
        o[0] = v0 - m - ls; o[1] = v1 - m - ls; o[2] = v2 - m - ls; o[3] = v3 - m - ls;
        __builtin_nontemporal_store(o, (floatx4*)&out[(size_t)node * F_OUT + 4 * p]);
    }
}

extern "C" void kernel_launch(void* const* d_in, const int* in_sizes, int n_in,
                              void* d_out, int out_size, void* d_ws, size_t ws_size,
                              hipStream_t stream) {
    const float* x = (const float*)d_in[0];
    const int* eidx = (const int*)d_in[1];   // int32 from harness
    const float* W1 = (const float*)d_in[2];
    const float* b1 = (const float*)d_in[3];
    const float* W2 = (const float*)d_in[4];
    const float* b2 = (const float*)d_in[5];
    float* out = (float*)d_out;

    char* ws = (char*)d_ws;
    int*   gcnt      = (int*)  (ws);                 // NBIN*CNT_PAD ints (12.5 KB)
    int*   dcnt      = (int*)  (ws + 16384);         // DEGB*CNT_PAD ints (4 KB)
    int*   rowptr    = (int*)  (ws + 400512);        // 100001 ints
    int*   perm      = (int*)  (ws + 800528);        // 100000 ints
    int*   csr_src   = (int*)  (ws + 1200528);       // 1.6M ints
    float* dinv      = (float*)(ws + 7600528);       // 100000
    short* W1t       = (short*)(ws + 8000528);       // 32768 bf16
    short* W2t       = (short*)(ws + 8066064);       // 6144 bf16
    unsigned char*  h1q   = (unsigned char*) (ws + 8078352);   // 4 planes x [N][32B] fp8 (12.8 MB)
    unsigned short* agg1b = (unsigned short*)(ws + 20878352);  // 12.8M bf16 (25.6 MB)
    unsigned int*   parts = (unsigned int*)  (ws + 20878352);  // 9.6 MB, dead before agg1b written
    unsigned char*  h2f8  = (unsigned char*) (ws + 46478352);  // 4M fp8 (4 MB)

    k_cvt_w<<<152, 256, 0, stream>>>(W1, W2, W1t, W2t, gcnt, dcnt);
    k_part<<<(N_EDGES + PART_CHUNK - 1) / PART_CHUNK, 256, 0, stream>>>(eidx, gcnt, parts);
    k_build<<<NBIN, 256, 0, stream>>>(parts, gcnt, rowptr, dinv, csr_src);

    k_dhist<<<(N_NODES + 1023) / 1024, 256, 0, stream>>>(rowptr, dcnt);
    k_dscan<<<1, 64, 0, stream>>>(dcnt);
    k_dscat<<<(N_NODES + 1023) / 1024, 256, 0, stream>>>(rowptr, dcnt, perm);

    k_gemm1_mfma<<<(N_NODES + 127) / 128, 256, 0, stream>>>(x, W1t, dinv, h1q);

    for (int pl = 0; pl < 4; ++pl)
        k_spmm1_q<<<(N_NODES + 127) / 128, 256, 0, stream>>>(
            rowptr, csr_src, perm,
            (const uintx4*)(h1q + (size_t)pl * N_NODES * 32),
            dinv, b1 + pl * 32, agg1b + pl * 32);

    k_gemm2_mfma<<<782, 256, 0, stream>>>(agg1b, W2t, dinv, h2f8);
    k_spmm2_lsm<<<(N_NODES + 15) / 16, 256, 0, stream>>>(rowptr, csr_src,
                                                         (const unsigned int*)h2f8, dinv, b2, out);
}

// Round 11
// 334.886 us; speedup vs baseline: 1.2115x; 1.2115x over previous
//
#include <hip/hip_runtime.h>
#include <hip/hip_fp8.h>
#include <math.h>

#define N_NODES 100000
#define N_EDGES 1600000
#define F_IN 256
#define F_H 128
#define F_OUT 40

// ---- CSR build via LDS-binned counting sort ----
#define BIN_SHIFT 9
#define BIN_NODES 512                       // 1 << BIN_SHIFT
#define NBIN 196                            // ceil(100000 / 512)
#define CAP 12288                           // per-bin capacity (mean 8163, sigma ~90)
#define CNT_PAD 16                          // one counter per 64B line
#define PART_CHUNK 8192                     // edges per k_part block

typedef __attribute__((ext_vector_type(8))) short bf16x8;
typedef __attribute__((ext_vector_type(4))) float floatx4;
typedef __attribute__((ext_vector_type(2))) float floatx2;
typedef __attribute__((ext_vector_type(2))) unsigned int uintx2;
typedef __attribute__((ext_vector_type(4))) unsigned int uintx4;

__device__ __forceinline__ unsigned short f2bf(float f) {
    unsigned int u = __float_as_uint(f);
    u += 0x7fffu + ((u >> 16) & 1u);          // RNE (finite inputs)
    return (unsigned short)(u >> 16);
}
__device__ __forceinline__ float bf2f(unsigned short s) { return __uint_as_float(((unsigned int)s) << 16); }

// ---- fp8 e4m3 (OCP) encode/decode, native cvt when available ----
#if defined(__has_builtin)
#if __has_builtin(__builtin_amdgcn_cvt_pk_fp8_f32)
#define HAVE_PK_ENC 1
#endif
#if __has_builtin(__builtin_amdgcn_cvt_pk_f32_fp8)
#define HAVE_PK_DEC 1
#endif
#if __has_builtin(__builtin_amdgcn_cvt_f32_fp8)
#define HAVE_SC_DEC 1
#endif
#endif

__device__ __forceinline__ unsigned char f2f8(float f) {
#ifdef HAVE_PK_ENC
    int r = __builtin_amdgcn_cvt_pk_fp8_f32(f, f, 0, false);
    return (unsigned char)(r & 0xff);
#else
    __hip_fp8_e4m3 t(f);
    return (unsigned char)t.__x;
#endif
}
__device__ __forceinline__ float f82f(unsigned char b) {
#ifdef HAVE_SC_DEC
    return __builtin_amdgcn_cvt_f32_fp8((int)b, 0);
#else
    __hip_fp8_e4m3 t; t.__x = (__hip_fp8_storage_t)b;
    return (float)t;
#endif
}
__device__ __forceinline__ floatx2 f8x2tof(unsigned short u) {
#ifdef HAVE_PK_DEC
    return __builtin_amdgcn_cvt_pk_f32_fp8((int)u, false);
#else
    floatx2 r;
    r.x = f82f((unsigned char)(u & 0xff));
    r.y = f82f((unsigned char)(u >> 8));
    return r;
#endif
}

// accumulate 16 fp8 (one uint4) into a[0..15]
__device__ __forceinline__ void acc16(uintx4 u, float* a) {
#pragma unroll
    for (int d = 0; d < 4; ++d) {
        floatx2 lo = f8x2tof((unsigned short)(u[d] & 0xffffu));
        floatx2 hi = f8x2tof((unsigned short)(u[d] >> 16));
        a[d * 4 + 0] += lo.x; a[d * 4 + 1] += lo.y;
        a[d * 4 + 2] += hi.x; a[d * 4 + 3] += hi.y;
    }
}

// ---- phase A: partition edges into NBIN dst-bins (packed src<<9|dloc) ----
__global__ __launch_bounds__(256) void k_part(const int* __restrict__ eidx,
                                              int* __restrict__ gcnt,
                                              unsigned int* __restrict__ parts) {
    __shared__ int hist[4][NBIN];
    __shared__ int sbase[NBIN];
    __shared__ int rcnt[NBIN];
    const int tid = threadIdx.x;
    const int wv = tid >> 6;
    for (int i = tid; i < NBIN; i += 256) {
        hist[0][i] = 0; hist[1][i] = 0; hist[2][i] = 0; hist[3][i] = 0; rcnt[i] = 0;
    }
    __syncthreads();
    const int e0 = blockIdx.x * PART_CHUNK;
    const int e1 = min(e0 + PART_CHUNK, N_EDGES);
    for (int e = e0 + tid; e < e1; e += 256) {
        int d = eidx[N_EDGES + e];
        atomicAdd(&hist[wv][d >> BIN_SHIFT], 1);
    }
    __syncthreads();
    for (int b = tid; b < NBIN; b += 256) {
        int tot = hist[0][b] + hist[1][b] + hist[2][b] + hist[3][b];
        int old = atomicAdd(&gcnt[b * CNT_PAD], tot);
        sbase[b] = b * CAP + old;
    }
    __syncthreads();
    for (int e = e0 + tid; e < e1; e += 256) {
        int d = eidx[N_EDGES + e];          // L2-hot re-read
        int s = eidx[e];
        int b = d >> BIN_SHIFT;
        int r = atomicAdd(&rcnt[b], 1);
        parts[sbase[b] + r] = ((unsigned int)s << BIN_SHIFT) | (unsigned int)(d & (BIN_NODES - 1));
    }
}

// ---- phase B: per-bin CSR build; block g owns nodes [g*512, g*512+512) ----
__global__ __launch_bounds__(256) void k_build(const unsigned int* __restrict__ parts,
                                               const int* __restrict__ gcnt,
                                               int* __restrict__ rowptr,
                                               float* __restrict__ dinv,
                                               int* __restrict__ csr_src) {
    __shared__ int deg[4][BIN_NODES];   // per-wave replicated histogram (8 KB)
    __shared__ int cur[BIN_NODES];
    __shared__ int scan[256];
    const int tid = threadIdx.x;
    const int wv = tid >> 6;
    const int g = blockIdx.x;

    // exclusive scan of bin sizes -> this bin's global edge base
    scan[tid] = (tid < NBIN) ? gcnt[tid * CNT_PAD] : 0;
    __syncthreads();
    for (int off = 1; off < 256; off <<= 1) {
        int v = 0;
        if (tid >= off) v = scan[tid - off];
        __syncthreads();
        if (tid >= off) scan[tid] += v;
        __syncthreads();
    }
    const int binBase = (g == 0) ? 0 : scan[g - 1];
    const int cntg = scan[g] - binBase;

    for (int i = tid; i < BIN_NODES; i += 256) {
        deg[0][i] = 0; deg[1][i] = 0; deg[2][i] = 0; deg[3][i] = 0;
    }
    __syncthreads();

    const unsigned int* pp = parts + (size_t)g * CAP;
    for (int i = tid; i < cntg; i += 256)
        atomicAdd(&deg[wv][pp[i] & (BIN_NODES - 1)], 1);
    __syncthreads();

    // block scan over 512 degrees (thread t owns nodes 2t, 2t+1)
    const int n0 = 2 * tid, n1 = 2 * tid + 1;
    const int d0 = deg[0][n0] + deg[1][n0] + deg[2][n0] + deg[3][n0];
    const int d1 = deg[0][n1] + deg[1][n1] + deg[2][n1] + deg[3][n1];
    scan[tid] = d0 + d1;
    __syncthreads();
    for (int off = 1; off < 256; off <<= 1) {
        int v = 0;
        if (tid >= off) v = scan[tid - off];
        __syncthreads();
        if (tid >= off) scan[tid] += v;
        __syncthreads();
    }
    const int pre = (tid == 0) ? 0 : scan[tid - 1];
    const int p0 = binBase + pre;
    const int p1 = p0 + d0;
    const int node0 = g * BIN_NODES + n0;
    if (node0 < N_NODES)     { rowptr[node0]     = p0; dinv[node0]     = rsqrtf((float)d0 + 1.0f); }
    if (node0 + 1 < N_NODES) { rowptr[node0 + 1] = p1; dinv[node0 + 1] = rsqrtf((float)d1 + 1.0f); }
    cur[n0] = p0;
    cur[n1] = p1;
    __syncthreads();

    for (int i = tid; i < cntg; i += 256) {
        unsigned int u = pp[i];
        int pos = atomicAdd(&cur[u & (BIN_NODES - 1)], 1);
        csr_src[pos] = (int)(u >> BIN_SHIFT);
    }
    if (g == NBIN - 1 && tid == 0) rowptr[N_NODES] = N_EDGES;
}

// ---- weight converts (merged): W1t [128][256] bf16, W2t [48][128] bf16 ----
__global__ void k_cvt_w(const float* __restrict__ W1, const float* __restrict__ W2,
                        short* __restrict__ W1t, short* __restrict__ W2t) {
    int b = blockIdx.x, t = threadIdx.x;
    if (b < 128) {
        int idx = b * 256 + t;                 // 32768
        int n = idx >> 8, k = idx & 255;
        W1t[n * 256 + k] = (short)f2bf(W1[k * 128 + n]);
    } else {
        int idx = (b - 128) * 256 + t;         // 6144
        if (idx < 48 * 128) {
            int n = idx >> 7, k = idx & 127;
            float v = (n < F_OUT) ? W2[k * F_OUT + n] : 0.f;
            W2t[n * 128 + k] = (short)f2bf(v);
        }
    }
}

// ---- GEMM1 (MFMA bf16, gemm2-style): h1f8[N,128](fp8) = dinv[row]*(x@W1) ----
// 128-row tile. Full-K B staged into LDS once; A staged per 32-k step.
__global__ __launch_bounds__(256) void k_gemm1_mfma(const float* __restrict__ x,
                                                    const short* __restrict__ W1t,
                                                    const float* __restrict__ dinv,
                                                    unsigned char* __restrict__ h1f8) {
    __shared__ short As[128 * 40];       // 10 KB, row stride 40 (80 B: 2-way banks, free)
    __shared__ short Bs[128 * 264];      // 67.6 KB, row stride 264
    __shared__ float Ds[128];
    const int tid = threadIdx.x;
    const int row0 = blockIdx.x * 128;
    const int w = tid >> 6, l = tid & 63;
    const int l15 = l & 15, q = l >> 4;
    const int ar = tid >> 1;             // 0..127
    const int ak = (tid & 1) * 16;       // 0 or 16

    // stage full B once: thread t covers row n=t>>1, k-half (t&1)*128
    {
        const int n = tid >> 1;
        const int kh = (tid & 1) * 128;
#pragma unroll
        for (int i = 0; i < 16; ++i)
            *(bf16x8*)&Bs[n * 264 + kh + i * 8] = *(const bf16x8*)&W1t[n * 256 + kh + i * 8];
    }
    if (tid < 128) {
        int r = row0 + tid;
        Ds[tid] = (r < N_NODES) ? dinv[r] : 0.f;
    }

    floatx4 acc[2][8];
#pragma unroll
    for (int a = 0; a < 2; ++a)
#pragma unroll
        for (int nt = 0; nt < 8; ++nt) acc[a][nt] = (floatx4)0.f;

    const bool arow_ok = (row0 + ar) < N_NODES;
    const float* xp = x + (size_t)(row0 + ar) * F_IN;

    for (int k0 = 0; k0 < F_IN; k0 += 32) {
        bf16x8 av0 = (bf16x8)0, av1 = (bf16x8)0;
        if (arow_ok) {
            floatx4 f0 = *(const floatx4*)(xp + k0 + ak);
            floatx4 f1 = *(const floatx4*)(xp + k0 + ak + 4);
            floatx4 f2 = *(const floatx4*)(xp + k0 + ak + 8);
            floatx4 f3 = *(const floatx4*)(xp + k0 + ak + 12);
            av0[0] = (short)f2bf(f0[0]); av0[1] = (short)f2bf(f0[1]);
            av0[2] = (short)f2bf(f0[2]); av0[3] = (short)f2bf(f0[3]);
            av0[4] = (short)f2bf(f1[0]); av0[5] = (short)f2bf(f1[1]);
            av0[6] = (short)f2bf(f1[2]); av0[7] = (short)f2bf(f1[3]);
            av1[0] = (short)f2bf(f2[0]); av1[1] = (short)f2bf(f2[1]);
            av1[2] = (short)f2bf(f2[2]); av1[3] = (short)f2bf(f2[3]);
            av1[4] = (short)f2bf(f3[0]); av1[5] = (short)f2bf(f3[1]);
            av1[6] = (short)f2bf(f3[2]); av1[7] = (short)f2bf(f3[3]);
        }
        __syncthreads();              // also covers the one-time B stage on k0==0
        *(bf16x8*)&As[ar * 40 + ak]     = av0;
        *(bf16x8*)&As[ar * 40 + ak + 8] = av1;
        __syncthreads();

        bf16x8 af[2], bfr[8];
#pragma unroll
        for (int a = 0; a < 2; ++a)
            af[a] = *(const bf16x8*)&As[((w * 2 + a) * 16 + l15) * 40 + q * 8];
#pragma unroll
        for (int nt = 0; nt < 8; ++nt)
            bfr[nt] = *(const bf16x8*)&Bs[(nt * 16 + l15) * 264 + k0 + q * 8];
#pragma unroll
        for (int a = 0; a < 2; ++a)
#pragma unroll
            for (int nt = 0; nt < 8; ++nt)
                acc[a][nt] = __builtin_amdgcn_mfma_f32_16x16x32_bf16(af[a], bfr[nt], acc[a][nt], 0, 0, 0);
    }
#pragma unroll
    for (int a = 0; a < 2; ++a) {
#pragma unroll
        for (int r = 0; r < 4; ++r) {
            const int rl = (w * 2 + a) * 16 + q * 4 + r;
            const int row = row0 + rl;
            if (row < N_NODES) {
                const float ds = Ds[rl];
                unsigned char* hp = h1f8 + (size_t)row * F_H;
#pragma unroll
                for (int nt = 0; nt < 8; ++nt)
                    hp[nt * 16 + l15] = f2f8(acc[a][nt][r] * ds);
            }
        }
    }
}

// ---- SpMM1: 8 lanes per node, 16B (uint4) per lane per edge gather ----
// One wave-instruction gathers for 8 nodes at once. XCD-contiguous node swizzle
// so agg1b writes stay in XCD-local L2 for gemm2 (matching swizzle there).
// agg1 = relu( dinv[d] * sum(h1 rows) + b1 ), rows pre-scaled by dinv[src].
__global__ __launch_bounds__(256) void k_spmm1(const int* __restrict__ rowptr,
                                               const int* __restrict__ csr_src,
                                               const uintx4* __restrict__ h1d4,   // fp8 rows as 8 uint4
                                               const float* __restrict__ dinv,
                                               const float* __restrict__ b1,
                                               unsigned short* __restrict__ agg1b) {
    const int slot = threadIdx.x >> 3;        // 0..31 node slot in block
    const int p = threadIdx.x & 7;            // 16B chunk in 128B row
    // bijective XCD-contiguous swizzle over 3125 blocks (3125 = 8*390+5)
    const int bid = blockIdx.x;
    const int k = bid & 7, j = bid >> 3;
    const int nb = (k < 5) ? (k * 391 + j) : (5 * 391 + (k - 5) * 390 + j);
    const int node = nb * 32 + slot;          // 3125*32 == 100000: always valid

    const int beg = rowptr[node];
    const int end = rowptr[node + 1];
    const float dv = dinv[node];

    float accA[16], accB[16];
#pragma unroll
    for (int jj = 0; jj < 16; ++jj) { accA[jj] = 0.f; accB[jj] = 0.f; }
    acc16(h1d4[(size_t)node * 8 + p], accA);          // self loop

    int i = beg;
    for (; i + 3 < end; i += 4) {
        int s0 = csr_src[i], s1 = csr_src[i + 1], s2 = csr_src[i + 2], s3 = csr_src[i + 3];
        uintx4 u0 = h1d4[(size_t)s0 * 8 + p];
        uintx4 u1 = h1d4[(size_t)s1 * 8 + p];
        uintx4 u2 = h1d4[(size_t)s2 * 8 + p];
        uintx4 u3 = h1d4[(size_t)s3 * 8 + p];
        acc16(u0, accA); acc16(u1, accB);
        acc16(u2, accA); acc16(u3, accB);
    }
    for (; i < end; ++i)
        acc16(h1d4[(size_t)csr_src[i] * 8 + p], accA);

    const float* bp = b1 + 16 * p;
    unsigned int ow[8];
#pragma unroll
    for (int jj = 0; jj < 8; ++jj) {
        float v0 = fmaf(accA[2 * jj]     + accB[2 * jj],     dv, bp[2 * jj]);
        float v1 = fmaf(accA[2 * jj + 1] + accB[2 * jj + 1], dv, bp[2 * jj + 1]);
        v0 = v0 > 0.f ? v0 : 0.f;
        v1 = v1 > 0.f ? v1 : 0.f;
        ow[jj] = ((unsigned int)f2bf(v1) << 16) | f2bf(v0);
    }
    uintx4* op = (uintx4*)(agg1b + (size_t)node * F_H) + 2 * p;
    uintx4 o0, o1;
    o0[0] = ow[0]; o0[1] = ow[1]; o0[2] = ow[2]; o0[3] = ow[3];
    o1[0] = ow[4]; o1[1] = ow[5]; o1[2] = ow[6]; o1[3] = ow[7];
    op[0] = o0;
    op[1] = o1;
}

// ---- GEMM2 (MFMA bf16): h2f8[N,40](fp8) = dinv[row] * (agg1b[N,128] @ W2) ----
// XCD-contiguous block swizzle matching spmm1's, so agg1b reads are L2-local.
__global__ __launch_bounds__(256) void k_gemm2_mfma(const unsigned short* __restrict__ agg1b,
                                                    const short* __restrict__ W2t,
                                                    const float* __restrict__ dinv,
                                                    unsigned char* __restrict__ h2f8) {
    __shared__ short As[128 * 40];     // 10 KB
    __shared__ short Bs[48 * 136];     // 12.75 KB
    __shared__ float Ds[128];
    const int tid = threadIdx.x;
    // bijective XCD-contiguous swizzle over 782 blocks (782 = 8*97+6)
    const int bidr = blockIdx.x;
    const int kx = bidr & 7, jx = bidr >> 3;
    const int cb = (kx < 6) ? (kx * 98 + jx) : (6 * 98 + (kx - 6) * 97 + jx);
    const int row0 = cb * 128;
    const int w = tid >> 6, l = tid & 63;
    const int l15 = l & 15, q = l >> 4;
    const int ar = tid >> 1;             // 0..127
    const int ak = (tid & 1) * 16;

#pragma unroll
    for (int i = 0; i < 3; ++i) {
        int c = tid * 3 + i;             // 0..767 chunks of 8 bf16
        int n = c >> 4, koff = (c & 15) * 8;
        *(bf16x8*)&Bs[n * 136 + koff] = *(const bf16x8*)&W2t[n * 128 + koff];
    }
    if (tid < 128) {
        int r = row0 + tid;
        Ds[tid] = (r < N_NODES) ? dinv[r] : 0.f;
    }

    floatx4 acc[2][3];
#pragma unroll
    for (int a = 0; a < 2; ++a)
#pragma unroll
        for (int nt = 0; nt < 3; ++nt) acc[a][nt] = (floatx4)0.f;

    const bool arow_ok = (row0 + ar) < N_NODES;
    const unsigned short* ap = agg1b + (size_t)(row0 + ar) * F_H;

    for (int k0 = 0; k0 < F_H; k0 += 32) {
        bf16x8 a0, a1;
        if (arow_ok) {
            a0 = *(const bf16x8*)(ap + k0 + ak);
            a1 = *(const bf16x8*)(ap + k0 + ak + 8);
        } else {
            a0 = (bf16x8)0; a1 = (bf16x8)0;
        }
        *(bf16x8*)&As[ar * 40 + ak]     = a0;
        *(bf16x8*)&As[ar * 40 + ak + 8] = a1;
        __syncthreads();

        bf16x8 af[2], bfr[3];
#pragma unroll
        for (int a = 0; a < 2; ++a)
            af[a] = *(const bf16x8*)&As[((w * 2 + a) * 16 + l15) * 40 + q * 8];
#pragma unroll
        for (int nt = 0; nt < 3; ++nt)
            bfr[nt] = *(const bf16x8*)&Bs[(nt * 16 + l15) * 136 + k0 + q * 8];
#pragma unroll
        for (int a = 0; a < 2; ++a)
#pragma unroll
            for (int nt = 0; nt < 3; ++nt)
                acc[a][nt] = __builtin_amdgcn_mfma_f32_16x16x32_bf16(af[a], bfr[nt], acc[a][nt], 0, 0, 0);
        __syncthreads();
    }
#pragma unroll
    for (int a = 0; a < 2; ++a) {
#pragma unroll
        for (int nt = 0; nt < 3; ++nt) {
            int col = nt * 16 + l15;
#pragma unroll
            for (int r = 0; r < 4; ++r) {
                int rl = (w * 2 + a) * 16 + q * 4 + r;
                int row = row0 + rl;
                if (row < N_NODES && col < F_OUT)
                    h2f8[(size_t)row * F_OUT + col] = f2f8(acc[a][nt][r] * Ds[rl]);
            }
        }
    }
}

// ---- SpMM2 + log_softmax: QUARTER-WAVE (16 lanes) per node; lanes 0..9 load dwords ----
__global__ __launch_bounds__(256) void k_spmm2_lsm(const int* __restrict__ rowptr,
                                                   const int* __restrict__ csr_src,
                                                   const unsigned int* __restrict__ h2d,  // fp8 rows as 10 dwords
                                                   const float* __restrict__ dinv,
                                                   const float* __restrict__ b2,
                                                   float* __restrict__ out) {
    const int qid = threadIdx.x >> 4;         // 0..15 node slot in block
    const int p = threadIdx.x & 15;           // dword index (active p<10)
    int node = blockIdx.x * 16 + qid;
    bool nvalid = node < N_NODES;
    bool valid = nvalid && (p < 10);
    int nd = nvalid ? node : 0;
    int beg = 0, end = 0;
    if (valid) { beg = rowptr[nd]; end = rowptr[nd + 1]; }
    float dv = dinv[nd];

    float A0 = 0.f, A1 = 0.f, A2 = 0.f, A3 = 0.f;
    float B0 = 0.f, B1 = 0.f, B2 = 0.f, B3 = 0.f;
    if (valid) {
        unsigned int su = h2d[(size_t)nd * 10 + p];
        floatx2 t0 = f8x2tof((unsigned short)(su & 0xffffu));
        floatx2 t1 = f8x2tof((unsigned short)(su >> 16));
        A0 = t0.x; A1 = t0.y; A2 = t1.x; A3 = t1.y;   // self loop
    }
    int i = beg;
    for (; i + 1 < end; i += 2) {
        int s0 = csr_src[i], s1 = csr_src[i + 1];
        unsigned int u0 = h2d[(size_t)s0 * 10 + p];
        unsigned int u1 = h2d[(size_t)s1 * 10 + p];
        floatx2 a01 = f8x2tof((unsigned short)(u0 & 0xffffu));
        floatx2 a23 = f8x2tof((unsigned short)(u0 >> 16));
        floatx2 b01 = f8x2tof((unsigned short)(u1 & 0xffffu));
        floatx2 b23 = f8x2tof((unsigned short)(u1 >> 16));
        A0 += a01.x; A1 += a01.y; A2 += a23.x; A3 += a23.y;
        B0 += b01.x; B1 += b01.y; B2 += b23.x; B3 += b23.y;
    }
    if (i < end) {
        unsigned int u0 = h2d[(size_t)csr_src[i] * 10 + p];
        floatx2 a01 = f8x2tof((unsigned short)(u0 & 0xffffu));
        floatx2 a23 = f8x2tof((unsigned short)(u0 >> 16));
        A0 += a01.x; A1 += a01.y; A2 += a23.x; A3 += a23.y;
    }

    float v0 = -INFINITY, v1 = -INFINITY, v2 = -INFINITY, v3 = -INFINITY;
    if (valid) {
        float4 bb = *(const float4*)&b2[4 * p];
        v0 = fmaf(A0 + B0, dv, bb.x);
        v1 = fmaf(A1 + B1, dv, bb.y);
        v2 = fmaf(A2 + B2, dv, bb.z);
        v3 = fmaf(A3 + B3, dv, bb.w);
    }
    float m = fmaxf(fmaxf(v0, v1), fmaxf(v2, v3));
#pragma unroll
    for (int off = 1; off < 16; off <<= 1) m = fmaxf(m, __shfl_xor(m, off, 16));
    float e = 0.f;
    if (valid) e = expf(v0 - m) + expf(v1 - m) + expf(v2 - m) + expf(v3 - m);
#pragma unroll
    for (int off = 1; off < 16; off <<= 1) e += __shfl_xor(e, off, 16);
    if (valid) {
        float ls = logf(e);
        floatx4 o;
        o[0] = v0 - m - ls; o[1] = v1 - m - ls; o[2] = v2 - m - ls; o[3] = v3 - m - ls;
        __builtin_nontemporal_store(o, (floatx4*)&out[(size_t)node * F_OUT + 4 * p]);
    }
}

extern "C" void kernel_launch(void* const* d_in, const int* in_sizes, int n_in,
                              void* d_out, int out_size, void* d_ws, size_t ws_size,
                              hipStream_t stream) {
    const float* x = (const float*)d_in[0];
    const int* eidx = (const int*)d_in[1];   // int32 from harness
    const float* W1 = (const float*)d_in[2];
    const float* b1 = (const float*)d_in[3];
    const float* W2 = (const float*)d_in[4];
    const float* b2 = (const float*)d_in[5];
    float* out = (float*)d_out;

    char* ws = (char*)d_ws;
    int*   gcnt      = (int*)  (ws);                 // NBIN*CNT_PAD ints (12.5 KB)
    int*   rowptr    = (int*)  (ws + 400512);        // 100001 ints
    int*   csr_src   = (int*)  (ws + 1200528);       // 1.6M ints
    float* dinv      = (float*)(ws + 7600528);       // 100000
    short* W1t       = (short*)(ws + 8000528);       // 32768 bf16
    short* W2t       = (short*)(ws + 8066064);       // 6144 bf16
    unsigned char*  h1f8  = (unsigned char*) (ws + 8078352);   // 12.8M fp8 (12.8 MB)
    unsigned short* agg1b = (unsigned short*)(ws + 20878352);  // 12.8M bf16 (25.6 MB)
    unsigned int*   parts = (unsigned int*)  (ws + 20878352);  // 9.6 MB, dead before agg1b written
    unsigned char*  h2f8  = (unsigned char*) (ws + 46478352);  // 4M fp8 (4 MB)

    // zero gcnt (3136 ints) via a tiny leading grid of k_cvt_w's tail branch
    hipMemsetAsync(gcnt, 0, NBIN * CNT_PAD * sizeof(int), stream);

    k_part<<<(N_EDGES + PART_CHUNK - 1) / PART_CHUNK, 256, 0, stream>>>(eidx, gcnt, parts);
    k_build<<<NBIN, 256, 0, stream>>>(parts, gcnt, rowptr, dinv, csr_src);

    k_cvt_w<<<152, 256, 0, stream>>>(W1, W2, W1t, W2t);

    k_gemm1_mfma<<<(N_NODES + 127) / 128, 256, 0, stream>>>(x, W1t, dinv, h1f8);
    k_spmm1<<<3125, 256, 0, stream>>>(rowptr, csr_src,
                                      (const uintx4*)h1f8, dinv, b1, agg1b);
    k_gemm2_mfma<<<782, 256, 0, stream>>>(agg1b, W2t, dinv, h2f8);
    k_spmm2_lsm<<<(N_NODES + 15) / 16, 256, 0, stream>>>(rowptr, csr_src,
                                                         (const unsigned int*)h2f8, dinv, b2, out);
}